// Round 1
// baseline (89.882 us; speedup 1.0000x reference)
//
#include <hip/hip_runtime.h>

#define NB 64
#define NT 128
#define ND 128
#define NE 512
#define HE 256
#define EPSV 1e-5f
#define XS_STR 144   // LDS row stride (shorts), 288B = 16B-aligned rows
#define A2_STR 272   // LDS row stride (shorts), 544B = 16B-aligned rows

typedef __bf16 bf16x8 __attribute__((ext_vector_type(8)));
typedef float f32x4 __attribute__((ext_vector_type(4)));

union Frag { unsigned short u[8]; bf16x8 v; };

__device__ __forceinline__ unsigned short f2bf(float f) {
  unsigned u = __float_as_uint(f);
  u += 0x7FFFu + ((u >> 16) & 1u);   // round-to-nearest-even
  return (unsigned short)(u >> 16);
}

// One block = (slot s, E-half h). Computes partial down-projection
// partial[s*2+h][b][d] = sum_{e in half} (up*silu(gate))[b,e] * Wd[s][e,d]
__global__ __launch_bounds__(512) void mlp_main(
    const float* __restrict__ Xsrc, const float* __restrict__ Wu,
    const float* __restrict__ bu, const float* __restrict__ Wg,
    const float* __restrict__ bg, const float* __restrict__ Wd,
    float* __restrict__ partial)
{
  const int s    = blockIdx.x >> 1;
  const int h    = blockIdx.x & 1;
  const int tid  = threadIdx.x;
  const int wv   = tid >> 6;    // 0..7
  const int lane = tid & 63;
  const int l16  = lane & 15;
  const int lg   = lane >> 4;   // 0..3

  __shared__ __align__(16) unsigned short Xs[NB * XS_STR];  // X[b][d] bf16
  __shared__ __align__(16) unsigned short A2[NB * A2_STR];  // (up*silu(gate))[b][e_local] bf16

  // Stage X: X[b,d] = Xsrc[b, d, s]  (transposed gather; source is L2-resident)
  for (int i = tid; i < NB * ND; i += 512) {
    const int b = i >> 7, d = i & 127;
    Xs[b * XS_STR + d] = f2bf(Xsrc[(((b << 7) + d) << 7) + s]);
  }
  __syncthreads();

  const float* WuS = Wu + (size_t)s * ND * NE;
  const float* WgS = Wg + (size_t)s * ND * NE;
  const int e0 = h * HE + wv * 32;   // this wave's first (global) e column

  f32x4 acc_u[2][4] = {};
  f32x4 acc_g[2][4] = {};

  // up/gate GEMM: M=64, K=128, N=32 per wave (2 n-tiles x 4 m-tiles)
  for (int kk = 0; kk < 4; ++kk) {
    const int k0 = kk * 32;
    Frag a[4];
#pragma unroll
    for (int mt = 0; mt < 4; ++mt)
      a[mt].v = *(const bf16x8*)&Xs[(mt * 16 + l16) * XS_STR + k0 + lg * 8];
#pragma unroll
    for (int n16 = 0; n16 < 2; ++n16) {
      const int e = e0 + n16 * 16 + l16;
      const float* pu = WuS + (size_t)(k0 + lg * 8) * NE + e;
      const float* pg = WgS + (size_t)(k0 + lg * 8) * NE + e;
      Frag fu, fg;
#pragma unroll
      for (int j = 0; j < 8; ++j) {
        fu.u[j] = f2bf(pu[(size_t)j * NE]);
        fg.u[j] = f2bf(pg[(size_t)j * NE]);
      }
#pragma unroll
      for (int mt = 0; mt < 4; ++mt) {
        acc_u[n16][mt] = __builtin_amdgcn_mfma_f32_16x16x32_bf16(a[mt].v, fu.v, acc_u[n16][mt], 0, 0, 0);
        acc_g[n16][mt] = __builtin_amdgcn_mfma_f32_16x16x32_bf16(a[mt].v, fg.v, acc_g[n16][mt], 0, 0, 0);
      }
    }
  }

  // bias + silu + multiply, write A2 to LDS (C/D layout: row=(lg*4+r), col=l16)
#pragma unroll
  for (int n16 = 0; n16 < 2; ++n16) {
    const int col = wv * 32 + n16 * 16 + l16;          // local e in [0,256)
    const float buv = bu[s * NE + h * HE + col];
    const float bgv = bg[s * NE + h * HE + col];
#pragma unroll
    for (int mt = 0; mt < 4; ++mt) {
#pragma unroll
      for (int r = 0; r < 4; ++r) {
        const int m = mt * 16 + lg * 4 + r;
        const float uv = acc_u[n16][mt][r] + buv;
        const float gv = acc_g[n16][mt][r] + bgv;
        A2[m * A2_STR + col] = f2bf(uv * (gv / (1.f + __expf(-gv))));
      }
    }
  }
  __syncthreads();

  // down GEMM: M=64, K=256 (this half), N=16 per wave
  const float* WdS = Wd + (size_t)s * NE * ND + (size_t)h * HE * ND;
  const int dcol = wv * 16 + l16;
  f32x4 acc_d[4] = {};
  for (int kk = 0; kk < 8; ++kk) {
    const int k0 = kk * 32;
    Frag fd;
    const float* pd = WdS + (size_t)(k0 + lg * 8) * ND + dcol;
#pragma unroll
    for (int j = 0; j < 8; ++j) fd.u[j] = f2bf(pd[(size_t)j * ND]);
#pragma unroll
    for (int mt = 0; mt < 4; ++mt) {
      Frag a2;
      a2.v = *(const bf16x8*)&A2[(mt * 16 + l16) * A2_STR + k0 + lg * 8];
      acc_d[mt] = __builtin_amdgcn_mfma_f32_16x16x32_bf16(a2.v, fd.v, acc_d[mt], 0, 0, 0);
    }
  }

  float* po = partial + (size_t)blockIdx.x * (NB * ND);
#pragma unroll
  for (int mt = 0; mt < 4; ++mt)
#pragma unroll
    for (int r = 0; r < 4; ++r)
      po[(mt * 16 + lg * 4 + r) * ND + dcol] = acc_d[mt][r];
}

// Reduce the two E-half partials, add down-bias + residual, RMSNorm, store
// y[b, s, d] (contiguous in d). Residual is Xsrc[b, d, s] (same gather form
// for both layers).
__global__ __launch_bounds__(256) void finish(
    const float* __restrict__ partial, const float* __restrict__ Xsrc,
    const float* __restrict__ bd, const float* __restrict__ scale,
    float* __restrict__ y)
{
  const int s = blockIdx.x;
  const int wv = threadIdx.x >> 6;
  const int lane = threadIdx.x & 63;
  const float* p0 = partial + (size_t)(s * 2) * (NB * ND);
  const float* p1 = p0 + NB * ND;
  for (int b = wv; b < NB; b += 4) {
    const int d0 = lane, d1 = lane + 64;
    float z0 = p0[b * ND + d0] + p1[b * ND + d0] + bd[s * ND + d0]
             + Xsrc[(((b << 7) + d0) << 7) + s];
    float z1 = p0[b * ND + d1] + p1[b * ND + d1] + bd[s * ND + d1]
             + Xsrc[(((b << 7) + d1) << 7) + s];
    float ss = z0 * z0 + z1 * z1;
#pragma unroll
    for (int off = 32; off; off >>= 1) ss += __shfl_xor(ss, off);
    const float inv = rsqrtf(ss * (1.f / 128.f) + EPSV);
    y[(((b << 7) + s) << 7) + d0] = z0 * inv * scale[d0];
    y[(((b << 7) + s) << 7) + d1] = z1 * inv * scale[d1];
  }
}

extern "C" void kernel_launch(void* const* d_in, const int* in_sizes, int n_in,
                              void* d_out, int out_size, void* d_ws, size_t ws_size,
                              hipStream_t stream) {
  (void)in_sizes; (void)n_in; (void)out_size; (void)ws_size;
  const float* x   = (const float*)d_in[0];
  const float* W1u = (const float*)d_in[1];
  const float* b1u = (const float*)d_in[2];
  const float* W1g = (const float*)d_in[3];
  const float* b1g = (const float*)d_in[4];
  const float* W1d = (const float*)d_in[5];
  const float* b1d = (const float*)d_in[6];
  const float* sc1 = (const float*)d_in[7];
  const float* W2u = (const float*)d_in[8];
  const float* b2u = (const float*)d_in[9];
  const float* W2g = (const float*)d_in[10];
  const float* b2g = (const float*)d_in[11];
  const float* W2d = (const float*)d_in[12];
  const float* b2d = (const float*)d_in[13];
  const float* sc2 = (const float*)d_in[14];
  float* out = (float*)d_out;

  float* x1s  = (float*)d_ws;                       // [B][H][T] layer-1 output, 4 MB
  float* part = x1s + (size_t)NB * NT * ND;         // [256][64][128] partials, 8 MB

  mlp_main<<<256, 512, 0, stream>>>(x,   W1u, b1u, W1g, b1g, W1d, part);
  finish <<<128, 256, 0, stream>>>(part, x,   b1d, sc1, x1s);
  mlp_main<<<256, 512, 0, stream>>>(x1s, W2u, b2u, W2g, b2g, W2d, part);
  finish <<<128, 256, 0, stream>>>(part, x1s, b2d, sc2, out);
}